// Round 1
// baseline (264.473 us; speedup 1.0000x reference)
//
#include <hip/hip_runtime.h>
#include <hip/hip_bf16.h>

#define K_DIM 64

typedef __attribute__((ext_vector_type(8))) __bf16 bf16x8;
typedef __attribute__((ext_vector_type(4))) float  f32x4;

// Kernel 1: row-normalize A and B (fp32) -> bf16 rows in workspace.
// One wave per row: 64 lanes == 64 elements.
__global__ __launch_bounds__(256) void normalize_bf16_kernel(
    const float* __restrict__ A, const float* __restrict__ B,
    __hip_bfloat16* __restrict__ An, __hip_bfloat16* __restrict__ Bn,
    int nA, int nB)
{
    int row  = blockIdx.x * 4 + (threadIdx.x >> 6);
    int lane = threadIdx.x & 63;
    if (row >= nA + nB) return;
    const float*      src = (row < nA) ? A  : B;
    __hip_bfloat16*   dst = (row < nA) ? An : Bn;
    int r = (row < nA) ? row : row - nA;

    float v = src[(size_t)r * K_DIM + lane];
    float s = v * v;
    #pragma unroll
    for (int off = 32; off >= 1; off >>= 1)
        s += __shfl_xor(s, off, 64);
    float inv = 1.0f / fmaxf(sqrtf(s), 1e-8f);   // matches max(||a||, eps)
    dst[(size_t)r * K_DIM + lane] = __float2bfloat16(v * inv);
}

// Kernel 2: C = An * Bn^T via bf16 MFMA, restructured as a streaming writer.
//
// Block = 128x128 tile, 4 waves; wave w owns rows [w*32, w*32+32) x 128 cols
// (2 m-tiles x 8 n-tiles of 16x16, K=64 -> 2 MFMA per tile).
//
// Key structural property: ALL global loads (A,B fragments -> registers) are
// issued before ANY global store. Loads and stores share vmcnt on CDNA; in
// the previous version each tm-slab's A-loads followed the prior slab's 16
// stores, so the MFMA waitcnt drained the store queue every slab. Here the
// drain is pure fire-and-forget.
//
// Drain: per-wave LDS transpose slab (16 rows x 132 f32, pad keeps staging
// <=2-way bank-aliased = free on CDNA4), then each store inst covers
// 2 rows x 512 B contiguous (vs 4 rows x 256 B before), rows ascending.
__global__ __launch_bounds__(256) void cosine_gemm_kernel(
    const f32x4* __restrict__ An, const f32x4* __restrict__ Bn,
    float* __restrict__ C, int N)
{
    __shared__ __align__(16) float smem[4][16][132];   // 33.8 KB total

    const int lane = threadIdx.x & 63;
    const int wave = threadIdx.x >> 6;
    const int l16  = lane & 15;
    const int quad = lane >> 4;                // 0..3
    const int gm0  = blockIdx.x * 128 + wave * 32;
    const int gn0  = blockIdx.y * 128;

    float (*buf)[132] = smem[wave];

    // B fragments for all 8 n-tiles: B[n = gn0+tn*16+l16][k = half*32+quad*8+j]
    // row is 64 bf16 = 8 float4s; float4 index within row = half*4 + quad.
    bf16x8 bfrag[8][2];
    #pragma unroll
    for (int tn = 0; tn < 8; ++tn) {
        size_t rb = (size_t)(gn0 + tn * 16 + l16) * 8;
        bfrag[tn][0] = __builtin_bit_cast(bf16x8, Bn[rb + quad]);
        bfrag[tn][1] = __builtin_bit_cast(bf16x8, Bn[rb + 4 + quad]);
    }

    // A fragments for both m-tiles of this wave (rows gm0..gm0+31).
    bf16x8 afrag[2][2];
    #pragma unroll
    for (int tm = 0; tm < 2; ++tm) {
        size_t ra = (size_t)(gm0 + tm * 16 + l16) * 8;
        afrag[tm][0] = __builtin_bit_cast(bf16x8, An[ra + quad]);
        afrag[tm][1] = __builtin_bit_cast(bf16x8, An[ra + 4 + quad]);
    }

    #pragma unroll
    for (int tm = 0; tm < 2; ++tm) {
        // Compute + stage one 16x128 slab. C/D layout (m89/m91):
        // col = l16, row = quad*4 + r. Staging banks: (4*row + col) % 32
        // -> quad contributes {0,16,0,16} -> 2-way max (free, m136).
        #pragma unroll
        for (int tn = 0; tn < 8; ++tn) {
            f32x4 a = {0.f, 0.f, 0.f, 0.f};
            a = __builtin_amdgcn_mfma_f32_16x16x32_bf16(afrag[tm][0], bfrag[tn][0], a, 0, 0, 0);
            a = __builtin_amdgcn_mfma_f32_16x16x32_bf16(afrag[tm][1], bfrag[tn][1], a, 0, 0, 0);
            #pragma unroll
            for (int r = 0; r < 4; ++r)
                buf[quad * 4 + r][tn * 16 + l16] = a[r];
        }

        // Drain: 8 store insts per slab; each inst = 2 rows x 512 B contiguous
        // (lanes 0-31 -> row 2i, lanes 32-63 -> row 2i+1). Per-wave buffer +
        // in-order same-wave DS ops => no __syncthreads needed; the next
        // slab's ds_writes are ordered behind these ds_reads by the DS pipe.
        #pragma unroll
        for (int i = 0; i < 8; ++i) {
            int rr = i * 2 + (lane >> 5);
            int cc = (lane & 31) * 4;
            f32x4 v = *(const f32x4*)&buf[rr][cc];
            *(f32x4*)&C[(size_t)(gm0 + tm * 16 + rr) * N + gn0 + cc] = v;
        }
    }
}

extern "C" void kernel_launch(void* const* d_in, const int* in_sizes, int n_in,
                              void* d_out, int out_size, void* d_ws, size_t ws_size,
                              hipStream_t stream) {
    const float* A = (const float*)d_in[0];
    const float* B = (const float*)d_in[1];
    int nA = in_sizes[0] / K_DIM;   // 8192
    int nB = in_sizes[1] / K_DIM;   // 8192
    float* C = (float*)d_out;

    __hip_bfloat16* An = (__hip_bfloat16*)d_ws;
    __hip_bfloat16* Bn = An + (size_t)nA * K_DIM;   // 2 MB total in d_ws

    int totalRows = nA + nB;
    normalize_bf16_kernel<<<dim3((totalRows + 3) / 4), dim3(256), 0, stream>>>(
        A, B, An, Bn, nA, nB);

    dim3 grid(nA / 128, nB / 128);
    cosine_gemm_kernel<<<grid, dim3(256), 0, stream>>>(
        (const f32x4*)An, (const f32x4*)Bn, C, nB);
}